// Round 12
// baseline (803.193 us; speedup 1.0000x reference)
//
#include <hip/hip_runtime.h>
#include <math.h>

typedef float    f4 __attribute__((ext_vector_type(4)));
typedef _Float16 h8 __attribute__((ext_vector_type(8)));
typedef _Float16 h4 __attribute__((ext_vector_type(4)));

static constexpr int cBS = 8, cB = 4, cM = 256, cD = 256, cN = 2048;
static constexpr size_t KV_ELEMS = (size_t)cBS * cB * cM * cD;      // 2,097,152 floats
static constexpr size_t KV_BYTES_F16 = 2 * KV_ELEMS * 2;            // Kh + VTh = 8 MB

// select v[c] (c in 0..3) with compile-time indices only (avoid scratch)
__device__ __forceinline__ float sel4(const float v[4], int c) {
  float s = v[0];
  s = (c == 1) ? v[1] : s;
  s = (c == 2) ? v[2] : s;
  s = (c == 3) ? v[3] : s;
  return s;
}

// blocks [0,512): transpose V -> VT (f16, [bk][d][m]); blocks [512,1536): K -> f16
__global__ __launch_bounds__(256) void k_prep(const f4* __restrict__ K,
                                              unsigned short* __restrict__ Kh,
                                              const float* __restrict__ V,
                                              unsigned short* __restrict__ VT) {
  __shared__ float t[64][65];
  int bid = blockIdx.x;
  int tid = threadIdx.x;
  if (bid < 512) {
    int dt = bid & 3, mt = (bid >> 2) & 3, bkk = bid >> 4; // bkk 0..31
    const float* src = V + (size_t)bkk * 65536 + (size_t)(mt * 64) * 256 + dt * 64;
#pragma unroll
    for (int i = 0; i < 4; ++i) {
      int idx = tid + i * 256;
      int r = idx >> 4, cq = idx & 15;
      f4 v = *(const f4*)(src + (size_t)r * 256 + cq * 4);
      t[r][cq * 4 + 0] = v[0]; t[r][cq * 4 + 1] = v[1];
      t[r][cq * 4 + 2] = v[2]; t[r][cq * 4 + 3] = v[3];
    }
    __syncthreads();
    _Float16* dst = reinterpret_cast<_Float16*>(VT) + (size_t)bkk * 65536 +
                    (size_t)(dt * 64) * 256 + mt * 64;
#pragma unroll
    for (int i = 0; i < 4; ++i) {
      int idx = tid + i * 256;
      int d = idx >> 4, mq = idx & 15;
      h4 h;
      h[0] = (_Float16)t[mq * 4 + 0][d];
      h[1] = (_Float16)t[mq * 4 + 1][d];
      h[2] = (_Float16)t[mq * 4 + 2][d];
      h[3] = (_Float16)t[mq * 4 + 3][d];
      *(h4*)(dst + (size_t)d * 256 + mq * 4) = h;
    }
  } else {
    int i = (bid - 512) * 256 + tid; // ×2 iters = 524,288 f4 = K size
    _Float16* kp = reinterpret_cast<_Float16*>(Kh);
#pragma unroll
    for (int j = 0; j < 2; ++j) {
      int idx = i + j * 262144;
      f4 v = K[idx];
      h4 h;
      h[0] = (_Float16)v[0]; h[1] = (_Float16)v[1];
      h[2] = (_Float16)v[2]; h[3] = (_Float16)v[3];
      *(h4*)(kp + (size_t)idx * 4) = h;
    }
  }
}

// 16-row tiles × all 4 k in one block: 1024 thr = 16 waves; wave wid: k = wid>>2,
// slice w = wid&3 (64-wide). Per-thread state = r7's proven-no-spill budget
// (y 16 + acc 16). In-kernel k-sum via 64KB LDS kills ypart/k_reduce/k_init
// (~80µs + 128MB HBM in r7). Occupancy: ~124 VGPR -> 16 waves/CU (VGPR-bound;
// the 99KB LDS -> 1 block/CU coincides, not binds).
template <bool PRE>
__global__ __launch_bounds__(1024)
void ep_main2(const float* __restrict__ seed, const float* __restrict__ emK,
              const float* __restrict__ emV, const float* __restrict__ emS,
              const float* __restrict__ galpha, const float* __restrict__ gbias,
              const float* __restrict__ rtau, const unsigned short* __restrict__ KhRaw,
              const unsigned short* __restrict__ VThRaw, float* __restrict__ out) {
  __shared__ alignas(16) _Float16 stage[4][16 * 256]; // 32KB: per-k y/P tile (swizzled)
  __shared__ alignas(16) float red[3][4][16][4];      // 3KB: max/sum/dot cross-wave
  __shared__ alignas(16) float ysum[4][16][256];      // 64KB: final k-sum

  const int tid = threadIdx.x, wid = tid >> 6, lane = tid & 63;
  const int g = lane >> 4, c = lane & 15;
  const int k = wid >> 2, w = wid & 3;
  const int bid = blockIdx.x;
  const int nt = bid & 127, b = bid >> 7;
  const int n0 = nt * 16, wm0 = w * 64, wd0 = w * 64;

  const float LOG2E = 1.4426950408889634f;
  float rt = rtau[k];
  float tau = ((rt > 20.f) ? rt : log1pf(expf(rt))) + 0.1f;
  float scale2 = LOG2E / tau;
  float ga = galpha[k] * (1.0f / 256.0f);
  float gb = gbias[k];

  const size_t bk = (size_t)(b * cB + k);
  float msk[4];
#pragma unroll
  for (int mh = 0; mh < 4; ++mh) {
    float sv = emS[bk * cM + wm0 + mh * 16 + c];
    msk[mh] = (sv > 0.f) ? 0.f : -1e30f;
  }

  // y state: y[dh][r] = y[n0+g*4+r][wd0+dh*16+c]  (16 f32/thread)
  float y[4][4];
  {
    const float* s0 = seed + (size_t)b * cN * cD;
#pragma unroll
    for (int r = 0; r < 4; ++r) {
      const float* rp = s0 + (size_t)(n0 + g * 4 + r) * cD + wd0 + c;
#pragma unroll
      for (int dh = 0; dh < 4; ++dh) y[dh][r] = rp[dh * 16];
    }
  }

  const _Float16* Kp = reinterpret_cast<const _Float16*>(KhRaw) + bk * cM * cD;
  const _Float16* VTp = reinterpret_cast<const _Float16*>(VThRaw) + bk * cD * cM;
  const float* Kf = emK + bk * cM * cD;
  const float* Vf = emV + bk * cM * cD;
  char* stg = (char*)&stage[k][0];

  f4 acc[4];
  float rmax[4], rsum[4];

  for (int step = 0; step < 2; ++step) {
    // ---- stage y as f16 (swizzled) ----
#pragma unroll
    for (int r = 0; r < 4; ++r) {
      int row = g * 4 + r;
      int sw = (row & 7) << 4;
#pragma unroll
      for (int dh = 0; dh < 4; ++dh) {
        int byte = ((row << 9) + ((wd0 + dh * 16 + c) << 1)) ^ sw;
        *(_Float16*)(stg + byte) = (_Float16)y[dh][r];
      }
    }
    __syncthreads();

    // ---- S = y @ K^T (wave owns m-slice wm0..wm0+63) ----
#pragma unroll
    for (int mh = 0; mh < 4; ++mh)
#pragma unroll
      for (int r = 0; r < 4; ++r) acc[mh][r] = 0.f;

    for (int kk = 0; kk < 8; ++kk) {
      h8 A, Bv[4];
      {
        int byte = ((c << 9) + (kk << 6) + (g << 4)) ^ ((c & 7) << 4);
        A = *(const h8*)(stg + byte);
      }
      if (PRE) {
#pragma unroll
        for (int mh = 0; mh < 4; ++mh)
          Bv[mh] = *(const h8*)(Kp + (size_t)(wm0 + mh * 16 + c) * cD + kk * 32 + g * 8);
      } else {
#pragma unroll
        for (int mh = 0; mh < 4; ++mh) {
          const float* p = Kf + (size_t)(wm0 + mh * 16 + c) * cD + kk * 32 + g * 8;
#pragma unroll
          for (int j = 0; j < 8; ++j) Bv[mh][j] = (_Float16)p[j];
        }
      }
#pragma unroll
      for (int mh = 0; mh < 4; ++mh)
        acc[mh] = __builtin_amdgcn_mfma_f32_16x16x32_f16(A, Bv[mh], acc[mh], 0, 0, 0);
    }

    // ---- scale + mask + wave row-max over its 64 cols ----
#pragma unroll
    for (int r = 0; r < 4; ++r) {
#pragma unroll
      for (int mh = 0; mh < 4; ++mh)
        acc[mh][r] = fmaf(acc[mh][r], scale2, msk[mh]);
      float v = fmaxf(fmaxf(acc[0][r], acc[1][r]), fmaxf(acc[2][r], acc[3][r]));
      v = fmaxf(v, __shfl_xor(v, 1, 64));
      v = fmaxf(v, __shfl_xor(v, 2, 64));
      v = fmaxf(v, __shfl_xor(v, 4, 64));
      v = fmaxf(v, __shfl_xor(v, 8, 64));
      rmax[r] = v;
    }
    if (c < 4) red[0][k][g * 4 + c][w] = sel4(rmax, c);
    __syncthreads();
#pragma unroll
    for (int r = 0; r < 4; ++r) {
      f4 q = *(const f4*)&red[0][k][g * 4 + r][0];
      rmax[r] = fmaxf(fmaxf(q[0], q[1]), fmaxf(q[2], q[3]));
    }

    // ---- exp + write P (f16) into stage (QK A-reads done before redmax barrier) ----
#pragma unroll
    for (int r = 0; r < 4; ++r) {
      int row = g * 4 + r;
      int sw = (row & 7) << 4;
#pragma unroll
      for (int mh = 0; mh < 4; ++mh) {
        acc[mh][r] = exp2f(acc[mh][r] - rmax[r]);
        int byte = ((row << 9) + ((wm0 + mh * 16 + c) << 1)) ^ sw;
        *(_Float16*)(stg + byte) = (_Float16)acc[mh][r];
      }
    }

    // ---- wave row-sum ----
#pragma unroll
    for (int r = 0; r < 4; ++r) {
      float v = (acc[0][r] + acc[1][r]) + (acc[2][r] + acc[3][r]);
      v += __shfl_xor(v, 1, 64);
      v += __shfl_xor(v, 2, 64);
      v += __shfl_xor(v, 4, 64);
      v += __shfl_xor(v, 8, 64);
      rsum[r] = v;
    }
    if (c < 4) red[1][k][g * 4 + c][w] = sel4(rsum, c);
    __syncthreads(); // also covers P-writes
#pragma unroll
    for (int r = 0; r < 4; ++r) {
      f4 q = *(const f4*)&red[1][k][g * 4 + r][0];
      float s = (q[0] + q[1]) + (q[2] + q[3]);
      rsum[r] = (s > 0.f && rmax[r] > -1e29f) ? (1.f / s) : 0.f;
    }

    // ---- delta = P @ V (wave owns d-slice wd0..wd0+63) ----
#pragma unroll
    for (int dh = 0; dh < 4; ++dh)
#pragma unroll
      for (int r = 0; r < 4; ++r) acc[dh][r] = 0.f;

    for (int kk = 0; kk < 8; ++kk) {
      h8 A, Bv[4];
      {
        int byte = ((c << 9) + (kk << 6) + (g << 4)) ^ ((c & 7) << 4);
        A = *(const h8*)(stg + byte);
      }
      if (PRE) {
#pragma unroll
        for (int dh = 0; dh < 4; ++dh)
          Bv[dh] = *(const h8*)(VTp + (size_t)(wd0 + dh * 16 + c) * cM + kk * 32 + g * 8);
      } else {
#pragma unroll
        for (int dh = 0; dh < 4; ++dh) {
#pragma unroll
          for (int j = 0; j < 8; ++j)
            Bv[dh][j] = (_Float16)Vf[(size_t)(kk * 32 + g * 8 + j) * cD + wd0 + dh * 16 + c];
        }
      }
#pragma unroll
      for (int dh = 0; dh < 4; ++dh)
        acc[dh] = __builtin_amdgcn_mfma_f32_16x16x32_f16(A, Bv[dh], acc[dh], 0, 0, 0);
    }

    // ---- normalize, dot (cross-wave), gate, update ----
    float dtp[4];
#pragma unroll
    for (int r = 0; r < 4; ++r) {
      float dp = 0.f;
#pragma unroll
      for (int dh = 0; dh < 4; ++dh) {
        acc[dh][r] *= rsum[r];
        dp = fmaf(y[dh][r], acc[dh][r], dp);
      }
      dp += __shfl_xor(dp, 1, 64);
      dp += __shfl_xor(dp, 2, 64);
      dp += __shfl_xor(dp, 4, 64);
      dp += __shfl_xor(dp, 8, 64);
      dtp[r] = dp;
    }
    if (c < 4) red[2][k][g * 4 + c][w] = sel4(dtp, c);
    __syncthreads(); // also covers all PV stage-reads before next-step stage write
#pragma unroll
    for (int r = 0; r < 4; ++r) {
      f4 q = *(const f4*)&red[2][k][g * 4 + r][0];
      float dot = (q[0] + q[1]) + (q[2] + q[3]);
      float x = fmaf(ga, dot, gb);
      float gate = 1.f / (1.f + exp2f(-LOG2E * x));
#pragma unroll
      for (int dh = 0; dh < 4; ++dh)
        y[dh][r] = fmaf(gate, acc[dh][r], y[dh][r]);
    }
  }

  // ---- in-kernel k-sum: y -> LDS, then out = sum_k y - 4*seed (coalesced) ----
#pragma unroll
  for (int r = 0; r < 4; ++r)
#pragma unroll
    for (int dh = 0; dh < 4; ++dh)
      ysum[k][g * 4 + r][wd0 + dh * 16 + c] = y[dh][r];
  __syncthreads();
  {
    int row = tid >> 6, c4 = tid & 63;
    f4 s4 = *(const f4*)&ysum[0][row][c4 * 4];
    s4 += *(const f4*)&ysum[1][row][c4 * 4];
    s4 += *(const f4*)&ysum[2][row][c4 * 4];
    s4 += *(const f4*)&ysum[3][row][c4 * 4];
    size_t idx = ((size_t)b * cN + n0 + row) * 64 + c4;
    f4 sd = ((const f4*)seed)[idx];
    ((f4*)out)[idx] = s4 - 4.0f * sd;
  }
}

extern "C" void kernel_launch(void* const* d_in, const int* in_sizes, int n_in,
                              void* d_out, int out_size, void* d_ws, size_t ws_size,
                              hipStream_t stream) {
  const float* seed = (const float*)d_in[0];
  const float* emK = (const float*)d_in[1];
  const float* emV = (const float*)d_in[2];
  const float* emS = (const float*)d_in[3];
  const float* ga = (const float*)d_in[4];
  const float* gb = (const float*)d_in[5];
  const float* rt = (const float*)d_in[6];
  float* out = (float*)d_out;

  unsigned short* Kh = (unsigned short*)d_ws;
  bool pre = (d_ws != nullptr) && (ws_size >= KV_BYTES_F16);
  unsigned short* VTh = pre ? (Kh + KV_ELEMS) : Kh;

  if (pre) {
    k_prep<<<dim3(1536), dim3(256), 0, stream>>>((const f4*)emK, Kh, emV, VTh);
    ep_main2<true><<<dim3(1024), dim3(1024), 0, stream>>>(seed, emK, emV, emS, ga, gb,
                                                          rt, Kh, VTh, out);
  } else {
    ep_main2<false><<<dim3(1024), dim3(1024), 0, stream>>>(seed, emK, emV, emS, ga, gb,
                                                           rt, Kh, VTh, out);
  }
}